// Round 1
// baseline (455.601 us; speedup 1.0000x reference)
//
#include <hip/hip_runtime.h>
#include <hip/hip_bf16.h>
#include <math.h>

#define N_NODES 50000
#define F_IN 128
#define HC 128
#define N_EDGES 800000
#define E_TOT (N_EDGES + N_NODES)   // 850000
#define NEG_SLOPE 0.2f
#define GN_EPS 1e-5f

// ---------------------------------------------------------------- init
__global__ __launch_bounds__(256) void init_k(int* __restrict__ deg,
                                              float* __restrict__ gsum,
                                              float* __restrict__ gsumsq) {
    int i = blockIdx.x * 256 + threadIdx.x;
    if (i < N_NODES) deg[i] = 0;
    if (i < HC) { gsum[i] = 0.f; gsumsq[i] = 0.f; }
}

// ---------------------------------------------------------------- GEMM (fp32 vector)
// x [N,128] @ W [128,128] -> out [N,128]; blockIdx.y selects (W_l->xl) / (W_r->xr)
// 256 threads, tile 64 rows x 128 cols, K chunked by 64.
__global__ __launch_bounds__(256) void gemm_k(const float* __restrict__ x,
                                              const float* __restrict__ Wl,
                                              const float* __restrict__ Wr,
                                              float* __restrict__ xl,
                                              float* __restrict__ xr) {
    const float* W = blockIdx.y ? Wr : Wl;
    float* out = blockIdx.y ? xr : xl;
    __shared__ float As[64][68];    // 68*4=272B row stride, 16B aligned
    __shared__ float Bs[128][68];   // transposed: Bs[col][k]
    const int tid = threadIdx.x;
    const int row0 = blockIdx.x * 64;
    float acc[8][4];
#pragma unroll
    for (int r = 0; r < 8; ++r)
#pragma unroll
        for (int c = 0; c < 4; ++c) acc[r][c] = 0.f;
    const int tcol = tid & 31;      // cols 4*tcol .. +3
    const int trow = tid >> 5;      // rows trow + 8*r

    for (int k0 = 0; k0 < 128; k0 += 64) {
        // stage A: 64 rows x 64 k
        {
            int arow = tid >> 2, aseg = (tid & 3) * 16;
            int grow = row0 + arow;
            const float* ap = x + (size_t)(grow < N_NODES ? grow : (N_NODES - 1)) * F_IN + k0 + aseg;
            float4 v0 = *(const float4*)(ap + 0);
            float4 v1 = *(const float4*)(ap + 4);
            float4 v2 = *(const float4*)(ap + 8);
            float4 v3 = *(const float4*)(ap + 12);
            *(float4*)&As[arow][aseg + 0]  = v0;
            *(float4*)&As[arow][aseg + 4]  = v1;
            *(float4*)&As[arow][aseg + 8]  = v2;
            *(float4*)&As[arow][aseg + 12] = v3;
        }
        // stage B transposed
        {
            int col4 = (tid & 31) * 4, kr = tid >> 5;
#pragma unroll
            for (int i = 0; i < 8; ++i) {
                int k = k0 + kr + 8 * i;
                float4 wv = *(const float4*)(W + (size_t)k * HC + col4);
                Bs[col4 + 0][k - k0] = wv.x;
                Bs[col4 + 1][k - k0] = wv.y;
                Bs[col4 + 2][k - k0] = wv.z;
                Bs[col4 + 3][k - k0] = wv.w;
            }
        }
        __syncthreads();
#pragma unroll 4
        for (int k = 0; k < 64; k += 4) {
            float4 b0 = *(float4*)&Bs[tcol * 4 + 0][k];
            float4 b1 = *(float4*)&Bs[tcol * 4 + 1][k];
            float4 b2 = *(float4*)&Bs[tcol * 4 + 2][k];
            float4 b3 = *(float4*)&Bs[tcol * 4 + 3][k];
#pragma unroll
            for (int r = 0; r < 8; ++r) {
                float4 a = *(float4*)&As[trow + 8 * r][k];
                acc[r][0] += a.x * b0.x + a.y * b0.y + a.z * b0.z + a.w * b0.w;
                acc[r][1] += a.x * b1.x + a.y * b1.y + a.z * b1.z + a.w * b1.w;
                acc[r][2] += a.x * b2.x + a.y * b2.y + a.z * b2.z + a.w * b2.w;
                acc[r][3] += a.x * b3.x + a.y * b3.y + a.z * b3.z + a.w * b3.w;
            }
        }
        __syncthreads();
    }
#pragma unroll
    for (int r = 0; r < 8; ++r) {
        int grow = row0 + trow + 8 * r;
        if (grow < N_NODES) {
            float4 o = make_float4(acc[r][0], acc[r][1], acc[r][2], acc[r][3]);
            *(float4*)(out + (size_t)grow * HC + tcol * 4) = o;
        }
    }
}

// ---------------------------------------------------------------- degree histogram
__global__ __launch_bounds__(256) void hist_k(const int* __restrict__ ei,
                                              int* __restrict__ deg) {
    int e = blockIdx.x * 256 + threadIdx.x;
    if (e >= E_TOT) return;
    int dst = (e < N_EDGES) ? ei[N_EDGES + e] : (e - N_EDGES);
    atomicAdd(&deg[dst], 1);
}

// ---------------------------------------------------------------- exclusive scan (1 block)
__global__ __launch_bounds__(1024) void scan_k(const int* __restrict__ deg,
                                               int* __restrict__ rowptr,
                                               int* __restrict__ cursor) {
    const int CHUNK = 49;   // 1024*49 = 50176 >= 50000
    int tid = threadIdx.x, lane = tid & 63, wid = tid >> 6;
    int base = tid * CHUNK;
    int local[CHUNK];
    int sum = 0;
#pragma unroll
    for (int j = 0; j < CHUNK; ++j) {
        int i = base + j;
        int v = (i < N_NODES) ? deg[i] : 0;
        local[j] = sum;
        sum += v;
    }
    int incl = sum;
#pragma unroll
    for (int d = 1; d < 64; d <<= 1) {
        int t = __shfl_up(incl, d, 64);
        if (lane >= d) incl += t;
    }
    __shared__ int wtot[16];
    __shared__ int woff[16];
    if (lane == 63) wtot[wid] = incl;
    __syncthreads();
    if (tid == 0) {
        int run = 0;
#pragma unroll
        for (int w = 0; w < 16; ++w) { woff[w] = run; run += wtot[w]; }
    }
    __syncthreads();
    int excl = woff[wid] + incl - sum;
#pragma unroll
    for (int j = 0; j < CHUNK; ++j) {
        int i = base + j;
        if (i < N_NODES) {
            int val = excl + local[j];
            rowptr[i] = val;
            cursor[i] = val;
        }
    }
    if (tid == 1023) rowptr[N_NODES] = excl + sum;   // total = E_TOT
}

// ---------------------------------------------------------------- CSR fill
__global__ __launch_bounds__(256) void fill_k(const int* __restrict__ ei,
                                              int* __restrict__ cursor,
                                              int* __restrict__ csr) {
    int e = blockIdx.x * 256 + threadIdx.x;
    if (e >= E_TOT) return;
    int src, dst;
    if (e < N_EDGES) { src = ei[e]; dst = ei[N_EDGES + e]; }
    else             { src = dst = e - N_EDGES; }
    int pos = atomicAdd(&cursor[dst], 1);
    csr[pos] = src;
}

// ---------------------------------------------------------------- fused attention (one wave per dst, online softmax)
__global__ __launch_bounds__(256) void attn_k(const float* __restrict__ xl,
                                              const float* __restrict__ xr,
                                              const int* __restrict__ rowptr,
                                              const int* __restrict__ csr,
                                              const float* __restrict__ att,
                                              const float* __restrict__ bias,
                                              float* __restrict__ out) {
    const int wid = threadIdx.x >> 6, lane = threadIdx.x & 63;
    const int dst = blockIdx.x * 4 + wid;
    if (dst >= N_NODES) return;
    // lane holds channels 2*lane, 2*lane+1 -> head = lane/16
    const float2 xrv = *(const float2*)(xr + (size_t)dst * HC + lane * 2);
    const float2 av  = *(const float2*)(att + lane * 2);
    float m = -INFINITY, l = 0.f, a0 = 0.f, a1 = 0.f;
    const int start = rowptr[dst], end = rowptr[dst + 1];
    for (int kb = start; kb < end; kb += 64) {
        int idx = kb + lane;
        int sv = (idx < end) ? csr[idx] : 0;
        int nk = min(64, end - kb);
        for (int j = 0; j < nk; ++j) {
            int src = __shfl(sv, j, 64);
            float2 xlv = *(const float2*)(xl + (size_t)src * HC + lane * 2);
            float t0 = xlv.x + xrv.x; t0 = (t0 > 0.f) ? t0 : NEG_SLOPE * t0;
            float t1 = xlv.y + xrv.y; t1 = (t1 > 0.f) ? t1 : NEG_SLOPE * t1;
            float part = av.x * t0 + av.y * t1;
            // reduce over the 16 lanes of this head
            part += __shfl_xor(part, 1, 16);
            part += __shfl_xor(part, 2, 16);
            part += __shfl_xor(part, 4, 16);
            part += __shfl_xor(part, 8, 16);
            // online softmax update
            float mnew = fmaxf(m, part);
            float sc = __expf(m - mnew);
            float p  = __expf(part - mnew);
            a0 = a0 * sc + p * xlv.x;
            a1 = a1 * sc + p * xlv.y;
            l  = l * sc + p;
            m = mnew;
        }
    }
    float inv = 1.0f / l;
    float2 bv = *(const float2*)(bias + lane * 2);
    float2 o;
    o.x = a0 * inv + bv.x;
    o.y = a1 * inv + bv.y;
    *(float2*)(out + (size_t)dst * HC + lane * 2) = o;
}

// ---------------------------------------------------------------- per-feature sum/sumsq
__global__ __launch_bounds__(256) void stats_k(const float* __restrict__ out,
                                               float* __restrict__ gsum,
                                               float* __restrict__ gsumsq) {
    int f = threadIdx.x & 127;
    int half = threadIdx.x >> 7;
    float s = 0.f, s2 = 0.f;
    for (int r = blockIdx.x * 2 + half; r < N_NODES; r += gridDim.x * 2) {
        float v = out[(size_t)r * HC + f];
        s += v; s2 += v * v;
    }
    __shared__ float l1[256], l2[256];
    l1[threadIdx.x] = s; l2[threadIdx.x] = s2;
    __syncthreads();
    if (threadIdx.x < 128) {
        s  = l1[threadIdx.x] + l1[threadIdx.x + 128];
        s2 = l2[threadIdx.x] + l2[threadIdx.x + 128];
        atomicAdd(&gsum[f], s);
        atomicAdd(&gsumsq[f], s2);
    }
}

// ---------------------------------------------------------------- GraphNorm finalize (in place on d_out)
__global__ __launch_bounds__(256) void norm_k(float* __restrict__ out,
                                              const float* __restrict__ gsum,
                                              const float* __restrict__ gsumsq,
                                              const float* __restrict__ gw,
                                              const float* __restrict__ gb,
                                              const float* __restrict__ gms) {
    int f = threadIdx.x & 127;
    int half = threadIdx.x >> 7;
    const float invN = 1.0f / (float)N_NODES;
    float mean = gsum[f] * invN;
    float msq  = gsumsq[f] * invN;
    float g = gms[f];
    float var = msq - 2.f * g * mean * mean + g * g * mean * mean;
    float rstd = rsqrtf(var + GN_EPS);
    float a = gw[f] * rstd;
    float b = gb[f] - a * g * mean;
    for (int r = blockIdx.x * 2 + half; r < N_NODES; r += gridDim.x * 2) {
        size_t o = (size_t)r * HC + f;
        out[o] = a * out[o] + b;
    }
}

// ---------------------------------------------------------------- launch
extern "C" void kernel_launch(void* const* d_in, const int* in_sizes, int n_in,
                              void* d_out, int out_size, void* d_ws, size_t ws_size,
                              hipStream_t stream) {
    const float* x    = (const float*)d_in[0];
    const int*   ei   = (const int*)d_in[1];
    const float* Wl   = (const float*)d_in[2];
    const float* Wr   = (const float*)d_in[3];
    const float* att  = (const float*)d_in[4];
    const float* bias = (const float*)d_in[5];
    const float* gw   = (const float*)d_in[6];
    const float* gb   = (const float*)d_in[7];
    const float* gms  = (const float*)d_in[8];
    float* out = (float*)d_out;

    // workspace layout (floats/ints), total ~55.2 MB
    float* xl     = (float*)d_ws;
    float* xr     = xl + (size_t)N_NODES * HC;
    float* gsum   = xr + (size_t)N_NODES * HC;
    float* gsumsq = gsum + HC;
    int*   deg    = (int*)(gsumsq + HC);
    int*   rowptr = deg + N_NODES;
    int*   cursor = rowptr + (N_NODES + 1);
    int*   csr    = cursor + N_NODES;

    hipLaunchKernelGGL(init_k, dim3((N_NODES + 255) / 256), dim3(256), 0, stream,
                       deg, gsum, gsumsq);
    hipLaunchKernelGGL(gemm_k, dim3((N_NODES + 63) / 64, 2), dim3(256), 0, stream,
                       x, Wl, Wr, xl, xr);
    hipLaunchKernelGGL(hist_k, dim3((E_TOT + 255) / 256), dim3(256), 0, stream,
                       ei, deg);
    hipLaunchKernelGGL(scan_k, dim3(1), dim3(1024), 0, stream,
                       deg, rowptr, cursor);
    hipLaunchKernelGGL(fill_k, dim3((E_TOT + 255) / 256), dim3(256), 0, stream,
                       ei, cursor, csr);
    hipLaunchKernelGGL(attn_k, dim3((N_NODES + 3) / 4), dim3(256), 0, stream,
                       xl, xr, rowptr, csr, att, bias, out);
    hipLaunchKernelGGL(stats_k, dim3(256), dim3(256), 0, stream,
                       out, gsum, gsumsq);
    hipLaunchKernelGGL(norm_k, dim3(512), dim3(256), 0, stream,
                       out, gsum, gsumsq, gw, gb, gms);
}